// Round 12
// baseline (84.765 us; speedup 1.0000x reference)
//
#include <hip/hip_runtime.h>
#include <cstdint>
#include <cstddef>

#define BATCH 32
#define IMH 512
#define IMW 512
#define KMAX 256
#define NB 4096          // histogram bins: key bits [63:52] = sign|exp|3-mantissa

// K1: register rolling-window NMS. Wave = 256 cols (4/lane), RPW output rows.
#define RPW 8
#define NBLKX 2
#define NBLKY 16
#define NBLK (NBLKX * NBLKY)   // 32 blocks/image
#define LCAP 2048              // 256x32 tile: strict maxima <= 2048 (worst case)
#define FCAP 512               // flushed (locally top-256-pruned) per block, expected ~270

#define TPB2 512               // tail threads (8 waves)
#define PADCAP 2048            // tail survivor LDS capacity

typedef unsigned long long u64;
typedef unsigned short u16;

__device__ __forceinline__ float sigmoidf_(float x) {
    return 1.0f / (1.0f + expf(-x));
}
__device__ __forceinline__ float scoref_(float r, float u) {
    const float sg = sigmoidf_(r);
    return sg * sg * (1.0f - 0.35f * sigmoidf_(u));
}

// ---------------------------------------------------------------------------
// K1: fused score + 3x3 NMS (register rolling window) + per-block 4096-bin
// hist (full, stored u16) + LOCAL top-256 pruning: flush only keys with
// bin >= local_bstar (~270/block). A pruned key is beaten by >=256 same-block
// keys, so it cannot be in the global top-256 and cannot reach global bstar.
// key = (score_bits<<32) | ~idx -> unsigned desc == (score desc, idx asc).
// ---------------------------------------------------------------------------
__global__ __launch_bounds__(256)
void score_nms_kernel(const float* __restrict__ route,
                      const float* __restrict__ unc,
                      u64* __restrict__ cand,
                      int* __restrict__ blkcnt,
                      u16* __restrict__ blkhist) {
    const int b    = blockIdx.z;
    const int tid  = threadIdx.x;
    const int w    = tid >> 6;
    const int lane = tid & 63;
    const int y0   = (blockIdx.y * 4 + w) * RPW;
    const int x0   = blockIdx.x * 256 + lane * 4;
    const int blk  = blockIdx.y * NBLKX + blockIdx.x;

    __shared__ u64 lcand[LCAP];          // 16 KB
    __shared__ unsigned hist[NB];        // 16 KB
    __shared__ unsigned wsum[4];
    __shared__ int lcnt, lbstarS, fcnt;
    if (tid == 0) { lcnt = 0; lbstarS = 0; fcnt = 0; }
    for (int i = tid; i < NB; i += 256) hist[i] = 0;
    __syncthreads();

    const float* rB = route + (size_t)b * IMH * IMW;
    const float* uB = unc   + (size_t)b * IMH * IMW;

    int ex = -1;
    if (lane == 0)       ex = x0 - 1;
    else if (lane == 63) ex = x0 + 4;
    const bool eAct = (ex >= 0 && ex < IMW);

    const u64 laneMaskLt = (1ull << lane) - 1ull;

    float sP[4], hP1[4], hP2[4];
    #pragma unroll
    for (int j = 0; j < 4; ++j) { sP[j] = -INFINITY; hP1[j] = -INFINITY; hP2[j] = -INFINITY; }

    const int ylast = y0 + RPW;
    bool v = (y0 - 1 >= 0);
    float4 r4, u4; float er = 0.f, eu = 0.f;
    if (v) {
        r4 = *(const float4*)(rB + (size_t)(y0 - 1) * IMW + x0);
        u4 = *(const float4*)(uB + (size_t)(y0 - 1) * IMW + x0);
        if (eAct) { er = rB[(size_t)(y0 - 1) * IMW + ex]; eu = uB[(size_t)(y0 - 1) * IMW + ex]; }
    }

    for (int y = y0 - 1; y <= ylast; ++y) {
        const int yn = y + 1;
        const bool vn = (yn <= ylast) && (yn < IMH);
        float4 r4n, u4n; float ern = 0.f, eun = 0.f;
        if (vn) {
            r4n = *(const float4*)(rB + (size_t)yn * IMW + x0);
            u4n = *(const float4*)(uB + (size_t)yn * IMW + x0);
            if (eAct) { ern = rB[(size_t)yn * IMW + ex]; eun = uB[(size_t)yn * IMW + ex]; }
        }

        float sC[4], hmC[4];
        float es = -INFINITY;
        if (v && eAct) es = scoref_(er, eu);
        if (v) {
            sC[0] = scoref_(r4.x, u4.x);
            sC[1] = scoref_(r4.y, u4.y);
            sC[2] = scoref_(r4.z, u4.z);
            sC[3] = scoref_(r4.w, u4.w);
        } else {
            sC[0] = sC[1] = sC[2] = sC[3] = -INFINITY;
        }
        float lft = __shfl_up(sC[3], 1, 64);
        if (lane == 0) lft = es;
        float rgt = __shfl_down(sC[0], 1, 64);
        if (lane == 63) rgt = es;
        if (v) {
            hmC[0] = fmaxf(fmaxf(lft,   sC[0]), sC[1]);
            hmC[1] = fmaxf(fmaxf(sC[0], sC[1]), sC[2]);
            hmC[2] = fmaxf(fmaxf(sC[1], sC[2]), sC[3]);
            hmC[3] = fmaxf(fmaxf(sC[2], sC[3]), rgt);
        } else {
            hmC[0] = hmC[1] = hmC[2] = hmC[3] = -INFINITY;
        }

        if (y >= y0 + 1) {
            const int yo = y - 1;
            bool p[4]; int cntT = 0;
            #pragma unroll
            for (int j = 0; j < 4; ++j) {
                const float m9 = fmaxf(fmaxf(hP2[j], hP1[j]), hmC[j]);
                p[j] = (sP[j] >= m9);
                cntT += p[j] ? 1 : 0;
            }
            const u64 B0 = __ballot(cntT & 1);
            const u64 B1 = __ballot(cntT & 2);
            const u64 B2 = __ballot(cntT & 4);
            const int total = __popcll(B0) + 2 * __popcll(B1) + 4 * __popcll(B2);
            if (total > 0) {
                const int prefix = __popcll(B0 & laneMaskLt) + 2 * __popcll(B1 & laneMaskLt)
                                 + 4 * __popcll(B2 & laneMaskLt);
                int wbase = 0;
                if (lane == 0) wbase = atomicAdd(&lcnt, total);
                wbase = __shfl(wbase, 0, 64);
                int mb = wbase + prefix;
                #pragma unroll
                for (int j = 0; j < 4; ++j) {
                    if (p[j]) {
                        const unsigned idx = (unsigned)(yo * IMW + (x0 + j));
                        const u64 key = ((u64)__float_as_uint(sP[j]) << 32) | (unsigned)(~idx);
                        if (mb < LCAP) lcand[mb] = key;
                        ++mb;
                    }
                }
            }
        }

        #pragma unroll
        for (int j = 0; j < 4; ++j) { hP2[j] = hP1[j]; hP1[j] = hmC[j]; sP[j] = sC[j]; }
        r4 = r4n; u4 = u4n; er = ern; eu = eun; v = vn;
    }

    __syncthreads();
    const int m = (lcnt < LCAP) ? lcnt : LCAP;

    // full per-block histogram (used by tail for the EXACT global threshold bin)
    for (int i = tid; i < m; i += 256)
        atomicAdd(&hist[(unsigned)(lcand[i] >> 52)], 1u);
    __syncthreads();

    // store full hist as packed u16
    unsigned* hout = (unsigned*)(blkhist + ((size_t)b * NBLK + blk) * NB);
    for (int i = tid; i < NB / 2; i += 256)
        hout[i] = (hist[2 * i] & 0xFFFFu) | (hist[2 * i + 1] << 16);

    // ---- local threshold bin (keep block-local top-256 superset) ----
    unsigned cs0 = 0;
    #pragma unroll
    for (int j = 0; j < 16; ++j) cs0 += hist[tid * 16 + j];
    unsigned s = cs0;
    #pragma unroll
    for (int d = 1; d < 64; d <<= 1) {
        const unsigned vv = __shfl_down(s, d, 64);
        if (lane + d < 64) s += vv;
    }
    if (lane == 0) wsum[w] = s;
    __syncthreads();
    unsigned after = 0, totAll = 0;
    #pragma unroll
    for (int w2 = 0; w2 < 4; ++w2) {
        totAll += wsum[w2];
        if (w2 > w) after += wsum[w2];
    }
    const unsigned sufIncl = s + after;
    const unsigned sufExcl = sufIncl - cs0;
    if (totAll > (unsigned)KMAX && sufExcl < (unsigned)KMAX && sufIncl >= (unsigned)KMAX) {
        unsigned acc = sufExcl;
        for (int j = 15; j >= 0; --j) {
            const unsigned h = hist[tid * 16 + j];
            if (acc + h >= (unsigned)KMAX) { lbstarS = tid * 16 + j; break; }
            acc += h;
        }
    }
    __syncthreads();
    const unsigned lbstar = (unsigned)lbstarS;

    // ---- flush only keys with bin >= lbstar (~270) ----
    u64* seg = cand + ((size_t)b * NBLK + blk) * FCAP;
    for (int i = tid; i < m; i += 256) {
        u64 k = 0;
        bool pred = false;
        if (i < m) {
            k = lcand[i];
            pred = ((unsigned)(k >> 52) >= lbstar);
        }
        const u64 mb2 = __ballot(pred);
        if (mb2) {
            const int leader = __ffsll(mb2) - 1;
            const int wcount = __popcll(mb2);
            const int prefix = __popcll(mb2 & laneMaskLt);
            int wb_ = 0;
            if (lane == leader) wb_ = atomicAdd(&fcnt, wcount);
            wb_ = __shfl(wb_, leader, 64);
            if (pred) {
                const int pos = wb_ + prefix;
                if (pos < FCAP) seg[pos] = k;
            }
        }
    }
    __syncthreads();
    if (tid == 0) blkcnt[b * NBLK + blk] = (fcnt < FCAP) ? fcnt : FCAP;
}

// ---------------------------------------------------------------------------
// K2 (tail): 1 block/image x 512 threads.
//   merge 32 block-hists into REGISTERS (8 bins/thread)
//   2-barrier hierarchical suffix scan -> exact global threshold bin bstar
//   one flat scan of 32x512 flushed slots -> collect bin >= bstar (~300) in LDS
//   pad + bitonic sort descending (N = 512/1024/2048 runtime)
//   top-256 are keys[0..255] sorted -> ROI epilogue
// ---------------------------------------------------------------------------
__global__ __launch_bounds__(TPB2)
void tail_kernel(const u64* __restrict__ cand,
                 const int* __restrict__ blkcnt,
                 const u16* __restrict__ blkhist,
                 const float* __restrict__ scale,
                 const float* __restrict__ unc,
                 const int* __restrict__ imh,
                 const int* __restrict__ imw,
                 float* __restrict__ rois,
                 float* __restrict__ scoresOut,
                 float* __restrict__ validOut) {
    const int b    = blockIdx.x;
    const int tid  = threadIdx.x;
    const int lane = tid & 63;
    const int w    = tid >> 6;     // 8 waves

    __shared__ u64 keys[PADCAP];   // 16 KB
    __shared__ int segc[NBLK];
    __shared__ unsigned wsum[8];
    __shared__ int bstarS, nS;

    if (tid < NBLK) segc[tid] = blkcnt[b * NBLK + tid];
    if (tid == 0) { bstarS = 0; nS = 0; }

    // ---- merge 32 block-hists: thread owns bins 8t..8t+7 (2 u64 per blk) ----
    const u64* hb = (const u64*)(blkhist + (size_t)b * NBLK * NB);
    unsigned sbin[8] = {0, 0, 0, 0, 0, 0, 0, 0};
    #pragma unroll 8
    for (int blk = 0; blk < NBLK; ++blk) {
        const u64 q0 = hb[blk * (NB / 4) + 2 * tid];
        const u64 q1 = hb[blk * (NB / 4) + 2 * tid + 1];
        sbin[0] += (unsigned)(q0 & 0xFFFFu);
        sbin[1] += (unsigned)((q0 >> 16) & 0xFFFFu);
        sbin[2] += (unsigned)((q0 >> 32) & 0xFFFFu);
        sbin[3] += (unsigned)(q0 >> 48);
        sbin[4] += (unsigned)(q1 & 0xFFFFu);
        sbin[5] += (unsigned)((q1 >> 16) & 0xFFFFu);
        sbin[6] += (unsigned)((q1 >> 32) & 0xFFFFu);
        sbin[7] += (unsigned)(q1 >> 48);
    }
    unsigned cs0 = 0;
    #pragma unroll
    for (int j = 0; j < 8; ++j) cs0 += sbin[j];

    // ---- hierarchical suffix scan (2 barriers) -> bstar ----
    unsigned s = cs0;
    #pragma unroll
    for (int d = 1; d < 64; d <<= 1) {
        const unsigned vv = __shfl_down(s, d, 64);
        if (lane + d < 64) s += vv;
    }
    if (lane == 0) wsum[w] = s;
    __syncthreads();
    unsigned after = 0, totAll = 0;
    #pragma unroll
    for (int w2 = 0; w2 < 8; ++w2) {
        totAll += wsum[w2];
        if (w2 > w) after += wsum[w2];
    }
    const unsigned sufIncl = s + after;
    const unsigned sufExcl = sufIncl - cs0;
    if (totAll > (unsigned)KMAX && sufExcl < (unsigned)KMAX && sufIncl >= (unsigned)KMAX) {
        unsigned acc = sufExcl;
        for (int j = 7; j >= 0; --j) {
            const unsigned h = sbin[j];
            if (acc + h >= (unsigned)KMAX) { bstarS = 8 * tid + j; break; }
            acc += h;
        }
    }
    __syncthreads();
    const unsigned bstar = (unsigned)bstarS;

    // ---- collect all keys with bin >= bstar (guaranteed >= 256 if total >= 256) ----
    const u64 laneMaskLt = (1ull << lane) - 1ull;
    const u64* cb = cand + (size_t)b * NBLK * FCAP;
    for (int f = tid; f < NBLK * FCAP; f += TPB2) {
        const int blk = f >> 9;            // FCAP = 512
        const int i   = f & (FCAP - 1);
        const bool vld = (i < segc[blk]);
        u64 k = 0;
        if (vld) k = cb[f];
        const bool pred = vld && ((unsigned)(k >> 52) >= bstar);
        const u64 mb = __ballot(pred);
        if (mb) {
            const int leader = __ffsll(mb) - 1;
            const int wcount = __popcll(mb);
            const int prefix = __popcll(mb & laneMaskLt);
            int wb_ = 0;
            if (lane == leader) wb_ = atomicAdd(&nS, wcount);
            wb_ = __shfl(wb_, leader, 64);
            if (pred) {
                const int pos = wb_ + prefix;
                if (pos < PADCAP) keys[pos] = k;
            }
        }
    }
    __syncthreads();
    int n = nS;
    if (n > PADCAP) n = PADCAP;
    const int N = (n <= 512) ? 512 : ((n <= 1024) ? 1024 : 2048);
    for (int i = n + tid; i < N; i += TPB2) keys[i] = 0ull;
    __syncthreads();

    // ---- bitonic sort descending over keys[0..N) (keys unique; zeros sink) ----
    for (int k2 = 2; k2 <= N; k2 <<= 1) {
        for (int j = k2 >> 1; j > 0; j >>= 1) {
            for (int p = tid; p < (N >> 1); p += TPB2) {
                const int i   = ((p & ~(j - 1)) << 1) | (p & (j - 1));
                const int ixj = i | j;
                const u64 a   = keys[i];
                const u64 bb2 = keys[ixj];
                const bool desc = ((i & k2) == 0);
                if (desc ? (a < bb2) : (a > bb2)) {
                    keys[i]   = bb2;
                    keys[ixj] = a;
                }
            }
            __syncthreads();
        }
    }

    // ---- epilogue: keys[0..255] are the exact sorted top-256 ----
    if (tid < KMAX) {
        const u64 k = keys[tid];
        const float value = __uint_as_float((unsigned)(k >> 32));
        const bool valid  = (k != 0ull) && (value > 0.0f);

        float r0 = 0.f, r1 = 0.f, r2 = 0.f, r3 = 0.f, r4 = 0.f, sv = 0.f, vv = 0.f;
        if (valid) {
            const unsigned idx = ~(unsigned)(k & 0xFFFFFFFFull);
            const int y = (int)(idx / IMW);
            const int x = (int)(idx % IMW);
            const float cx = ((float)x + 0.5f) * 4.0f;
            const float cy = ((float)y + 0.5f) * 4.0f;
            const float sg = scale[(size_t)b * IMH * IMW + idx];
            const float uu = unc[(size_t)b * IMH * IMW + idx];
            const float su = sigmoidf_(uu);
            float side = 32.0f + sigmoidf_(sg) * (512.0f - 32.0f);
            side = side * (1.0f + 0.25f * su);
            const float half = side * 0.5f;
            const float fw = (float)imw[0];
            const float fh = (float)imh[0];
            r0 = (float)b;
            r1 = fminf(fmaxf(cx - half, 0.0f), fw - 1.0f);
            r2 = fminf(fmaxf(cy - half, 0.0f), fh - 1.0f);
            r3 = fminf(fmaxf(cx + half, 1.0f), fw);
            r4 = fminf(fmaxf(cy + half, 1.0f), fh);
            sv = value;
            vv = 1.0f;
        }
        float* roiP = rois + ((size_t)b * KMAX + tid) * 5;
        roiP[0] = r0; roiP[1] = r1; roiP[2] = r2; roiP[3] = r3; roiP[4] = r4;
        scoresOut[b * KMAX + tid] = sv;
        validOut[b * KMAX + tid]  = vv;
    }
}

extern "C" void kernel_launch(void* const* d_in, const int* in_sizes, int n_in,
                              void* d_out, int out_size, void* d_ws, size_t ws_size,
                              hipStream_t stream) {
    const float* route = (const float*)d_in[0];
    const float* scale = (const float*)d_in[1];
    const float* unc   = (const float*)d_in[2];
    const int*   imh   = (const int*)d_in[3];
    const int*   imw   = (const int*)d_in[4];

    // ws layout (~12.2 MB): [cand 4MB][blkcnt 4KB][blkhist u16 8MB]
    char* ws = (char*)d_ws;
    u64* cand    = (u64*)ws;
    size_t off   = (size_t)BATCH * NBLK * FCAP * sizeof(u64);
    int* blkcnt  = (int*)(ws + off);   off += (size_t)BATCH * NBLK * sizeof(int);
    u16* blkhist = (u16*)(ws + off);

    float* rois      = (float*)d_out;                       // [B, 256, 5]
    float* scoresOut = rois + (size_t)BATCH * KMAX * 5;     // [B, 256]
    float* validOut  = scoresOut + (size_t)BATCH * KMAX;    // [B, 256]

    dim3 grid1(NBLKX, NBLKY, BATCH);
    score_nms_kernel<<<grid1, 256, 0, stream>>>(route, unc, cand, blkcnt, blkhist);

    tail_kernel<<<BATCH, TPB2, 0, stream>>>(cand, blkcnt, blkhist, scale, unc,
                                            imh, imw, rois, scoresOut, validOut);
}

// Round 13
// 74.410 us; speedup vs baseline: 1.1392x; 1.1392x over previous
//
#include <hip/hip_runtime.h>
#include <cstdint>
#include <cstddef>

#define BATCH 32
#define IMH 512
#define IMW 512
#define KMAX 256

// K1: register rolling-window NMS. Wave = 256 cols (4/lane), RPW output rows.
#define RPW 8
#define NBLKX 2
#define NBLKY 16
#define NBLK (NBLKX * NBLKY)   // 32 blocks/image
#define LCAP 2048              // 256x32 tile: strict maxima <= 2048 (worst case)

#define TPB2 512               // tail threads (8 waves)

typedef unsigned long long u64;

__device__ __forceinline__ float sigmoidf_(float x) {
    return 1.0f / (1.0f + expf(-x));
}
__device__ __forceinline__ float scoref_(float r, float u) {
    const float sg = sigmoidf_(r);
    return sg * sg * (1.0f - 0.35f * sigmoidf_(u));
}

// ---------------------------------------------------------------------------
// K1: fused score + 3x3 NMS (register rolling window) + in-block bitonic sort
// of all candidates + flush of the block's SORTED top-256 (zero-padded, no
// counts). Tournament property: any global-top-256 key is in its own block's
// top-256, so the union of per-block top-256 lists is an exact superset.
// key = (score_bits<<32) | ~idx -> unsigned desc == (score desc, idx asc),
// matching lax.top_k's stable tie-break.
// ---------------------------------------------------------------------------
__global__ __launch_bounds__(256)
void score_nms_kernel(const float* __restrict__ route,
                      const float* __restrict__ unc,
                      u64* __restrict__ top) {
    const int b    = blockIdx.z;
    const int tid  = threadIdx.x;
    const int w    = tid >> 6;
    const int lane = tid & 63;
    const int y0   = (blockIdx.y * 4 + w) * RPW;
    const int x0   = blockIdx.x * 256 + lane * 4;
    const int blk  = blockIdx.y * NBLKX + blockIdx.x;

    __shared__ u64 lcand[LCAP];          // 16 KB
    __shared__ int lcnt;
    if (tid == 0) lcnt = 0;
    __syncthreads();

    const float* rB = route + (size_t)b * IMH * IMW;
    const float* uB = unc   + (size_t)b * IMH * IMW;

    int ex = -1;
    if (lane == 0)       ex = x0 - 1;
    else if (lane == 63) ex = x0 + 4;
    const bool eAct = (ex >= 0 && ex < IMW);

    const u64 laneMaskLt = (1ull << lane) - 1ull;

    float sP[4], hP1[4], hP2[4];
    #pragma unroll
    for (int j = 0; j < 4; ++j) { sP[j] = -INFINITY; hP1[j] = -INFINITY; hP2[j] = -INFINITY; }

    const int ylast = y0 + RPW;
    bool v = (y0 - 1 >= 0);
    float4 r4, u4; float er = 0.f, eu = 0.f;
    if (v) {
        r4 = *(const float4*)(rB + (size_t)(y0 - 1) * IMW + x0);
        u4 = *(const float4*)(uB + (size_t)(y0 - 1) * IMW + x0);
        if (eAct) { er = rB[(size_t)(y0 - 1) * IMW + ex]; eu = uB[(size_t)(y0 - 1) * IMW + ex]; }
    }

    for (int y = y0 - 1; y <= ylast; ++y) {
        const int yn = y + 1;
        const bool vn = (yn <= ylast) && (yn < IMH);
        float4 r4n, u4n; float ern = 0.f, eun = 0.f;
        if (vn) {
            r4n = *(const float4*)(rB + (size_t)yn * IMW + x0);
            u4n = *(const float4*)(uB + (size_t)yn * IMW + x0);
            if (eAct) { ern = rB[(size_t)yn * IMW + ex]; eun = uB[(size_t)yn * IMW + ex]; }
        }

        float sC[4], hmC[4];
        float es = -INFINITY;
        if (v && eAct) es = scoref_(er, eu);
        if (v) {
            sC[0] = scoref_(r4.x, u4.x);
            sC[1] = scoref_(r4.y, u4.y);
            sC[2] = scoref_(r4.z, u4.z);
            sC[3] = scoref_(r4.w, u4.w);
        } else {
            sC[0] = sC[1] = sC[2] = sC[3] = -INFINITY;
        }
        float lft = __shfl_up(sC[3], 1, 64);
        if (lane == 0) lft = es;
        float rgt = __shfl_down(sC[0], 1, 64);
        if (lane == 63) rgt = es;
        if (v) {
            hmC[0] = fmaxf(fmaxf(lft,   sC[0]), sC[1]);
            hmC[1] = fmaxf(fmaxf(sC[0], sC[1]), sC[2]);
            hmC[2] = fmaxf(fmaxf(sC[1], sC[2]), sC[3]);
            hmC[3] = fmaxf(fmaxf(sC[2], sC[3]), rgt);
        } else {
            hmC[0] = hmC[1] = hmC[2] = hmC[3] = -INFINITY;
        }

        if (y >= y0 + 1) {
            const int yo = y - 1;
            bool p[4]; int cntT = 0;
            #pragma unroll
            for (int j = 0; j < 4; ++j) {
                const float m9 = fmaxf(fmaxf(hP2[j], hP1[j]), hmC[j]);
                p[j] = (sP[j] >= m9);
                cntT += p[j] ? 1 : 0;
            }
            const u64 B0 = __ballot(cntT & 1);
            const u64 B1 = __ballot(cntT & 2);
            const u64 B2 = __ballot(cntT & 4);
            const int total = __popcll(B0) + 2 * __popcll(B1) + 4 * __popcll(B2);
            if (total > 0) {
                const int prefix = __popcll(B0 & laneMaskLt) + 2 * __popcll(B1 & laneMaskLt)
                                 + 4 * __popcll(B2 & laneMaskLt);
                int wbase = 0;
                if (lane == 0) wbase = atomicAdd(&lcnt, total);
                wbase = __shfl(wbase, 0, 64);
                int mb = wbase + prefix;
                #pragma unroll
                for (int j = 0; j < 4; ++j) {
                    if (p[j]) {
                        const unsigned idx = (unsigned)(yo * IMW + (x0 + j));
                        const u64 key = ((u64)__float_as_uint(sP[j]) << 32) | (unsigned)(~idx);
                        if (mb < LCAP) lcand[mb] = key;
                        ++mb;
                    }
                }
            }
        }

        #pragma unroll
        for (int j = 0; j < 4; ++j) { hP2[j] = hP1[j]; hP1[j] = hmC[j]; sP[j] = sC[j]; }
        r4 = r4n; u4 = u4n; er = ern; eu = eun; v = vn;
    }

    __syncthreads();
    const int m = (lcnt < LCAP) ? lcnt : LCAP;
    const int N = (m <= 1024) ? 1024 : 2048;

    // zero-pad and bitonic sort descending (keys unique; zeros sink)
    for (int i = m + tid; i < N; i += 256) lcand[i] = 0ull;
    __syncthreads();
    for (int k2 = 2; k2 <= N; k2 <<= 1) {
        for (int j = k2 >> 1; j > 0; j >>= 1) {
            for (int p = tid; p < (N >> 1); p += 256) {
                const int i   = ((p & ~(j - 1)) << 1) | (p & (j - 1));
                const int ixj = i | j;
                const u64 a = lcand[i];
                const u64 c = lcand[ixj];
                const bool desc = ((i & k2) == 0);
                if (desc ? (a < c) : (a > c)) {
                    lcand[i]   = c;
                    lcand[ixj] = a;
                }
            }
            __syncthreads();
        }
    }

    // flush the sorted top-256 (fixed location, no counts)
    u64* seg = top + ((size_t)b * NBLK + blk) * KMAX;
    seg[tid] = lcand[tid];
}

// ---------------------------------------------------------------------------
// K2 (tail): 1 block/image x 512 threads. 32 sorted-desc 256-lists ->
// 5 rounds of pairwise top-256 merge:
//   D[i] = max(A[i], B[255-i])   (exact top-256 of A∪B, bitonic)
//   + 8-phase bitonic merge -> sorted desc.
// Final list = exact sorted global top-256 -> ROI epilogue.
// ---------------------------------------------------------------------------
__global__ __launch_bounds__(TPB2)
void tail_kernel(const u64* __restrict__ top,
                 const float* __restrict__ scale,
                 const float* __restrict__ unc,
                 const int* __restrict__ imh,
                 const int* __restrict__ imw,
                 float* __restrict__ rois,
                 float* __restrict__ scoresOut,
                 float* __restrict__ validOut) {
    const int b   = blockIdx.x;
    const int tid = threadIdx.x;

    __shared__ u64 bufA[NBLK * KMAX];        // 64 KB
    __shared__ u64 bufB[(NBLK / 2) * KMAX];  // 32 KB

    // load 32 lists (coalesced)
    const u64* tb = top + (size_t)b * NBLK * KMAX;
    for (int i = tid; i < NBLK * KMAX; i += TPB2) bufA[i] = tb[i];
    __syncthreads();

    u64* src = bufA;
    u64* dst = bufB;
    int nl = NBLK;
    while (nl > 1) {
        const int half = nl >> 1;
        const int E = half * KMAX;
        // pairwise top-256 selection: D[i] = max(A[i], B[255-i])
        for (int p = tid; p < E; p += TPB2) {
            const int h = p >> 8;
            const int i = p & (KMAX - 1);
            const u64 a = src[(2 * h) * KMAX + i];
            const u64 c = src[(2 * h + 1) * KMAX + (KMAX - 1 - i)];
            dst[p] = (a > c) ? a : c;
        }
        __syncthreads();
        // bitonic merge each 256-group to sorted desc
        for (int j = KMAX >> 1; j > 0; j >>= 1) {
            for (int p = tid; p < (E >> 1); p += TPB2) {
                const int i   = ((p & ~(j - 1)) << 1) | (p & (j - 1));
                const int ixj = i | j;
                const u64 a = dst[i];
                const u64 c = dst[ixj];
                if (a < c) { dst[i] = c; dst[ixj] = a; }
            }
            __syncthreads();
        }
        u64* t = src; src = dst; dst = t;
        nl = half;
    }
    // src[0..255] = exact sorted top-256

    if (tid < KMAX) {
        const u64 k = src[tid];
        const float value = __uint_as_float((unsigned)(k >> 32));
        const bool valid  = (k != 0ull) && (value > 0.0f);

        float r0 = 0.f, r1 = 0.f, r2 = 0.f, r3 = 0.f, r4 = 0.f, sv = 0.f, vv = 0.f;
        if (valid) {
            const unsigned idx = ~(unsigned)(k & 0xFFFFFFFFull);
            const int y = (int)(idx / IMW);
            const int x = (int)(idx % IMW);
            const float cx = ((float)x + 0.5f) * 4.0f;
            const float cy = ((float)y + 0.5f) * 4.0f;
            const float sg = scale[(size_t)b * IMH * IMW + idx];
            const float uu = unc[(size_t)b * IMH * IMW + idx];
            const float su = sigmoidf_(uu);
            float side = 32.0f + sigmoidf_(sg) * (512.0f - 32.0f);
            side = side * (1.0f + 0.25f * su);
            const float half2 = side * 0.5f;
            const float fw = (float)imw[0];
            const float fh = (float)imh[0];
            r0 = (float)b;
            r1 = fminf(fmaxf(cx - half2, 0.0f), fw - 1.0f);
            r2 = fminf(fmaxf(cy - half2, 0.0f), fh - 1.0f);
            r3 = fminf(fmaxf(cx + half2, 1.0f), fw);
            r4 = fminf(fmaxf(cy + half2, 1.0f), fh);
            sv = value;
            vv = 1.0f;
        }
        float* roiP = rois + ((size_t)b * KMAX + tid) * 5;
        roiP[0] = r0; roiP[1] = r1; roiP[2] = r2; roiP[3] = r3; roiP[4] = r4;
        scoresOut[b * KMAX + tid] = sv;
        validOut[b * KMAX + tid]  = vv;
    }
}

extern "C" void kernel_launch(void* const* d_in, const int* in_sizes, int n_in,
                              void* d_out, int out_size, void* d_ws, size_t ws_size,
                              hipStream_t stream) {
    const float* route = (const float*)d_in[0];
    const float* scale = (const float*)d_in[1];
    const float* unc   = (const float*)d_in[2];
    const int*   imh   = (const int*)d_in[3];
    const int*   imw   = (const int*)d_in[4];

    // ws layout: [top B*NBLK*256 u64] = 2 MB
    u64* top = (u64*)d_ws;

    float* rois      = (float*)d_out;                       // [B, 256, 5]
    float* scoresOut = rois + (size_t)BATCH * KMAX * 5;     // [B, 256]
    float* validOut  = scoresOut + (size_t)BATCH * KMAX;    // [B, 256]

    dim3 grid1(NBLKX, NBLKY, BATCH);
    score_nms_kernel<<<grid1, 256, 0, stream>>>(route, unc, top);

    tail_kernel<<<BATCH, TPB2, 0, stream>>>(top, scale, unc,
                                            imh, imw, rois, scoresOut, validOut);
}